// Round 11
// baseline (94.652 us; speedup 1.0000x reference)
//
#include <hip/hip_runtime.h>
#include <hip/hip_bf16.h>

// Problem constants (from reference): B=16, N2=1024, N3=2048, D=128
#define NB   16
#define N2   1024
#define N3   2048
#define DD   128
#define OROWS (N3 + 1)   // 2049
#define OCOLS (N2 + 1)   // 1025

typedef __attribute__((ext_vector_type(8))) __bf16 bf16x8;
typedef __attribute__((ext_vector_type(4))) float  f32x4;

// Pack two f32 into one u32 of 2x bf16 (RNE). a -> low half, b -> high half.
static __device__ __forceinline__ unsigned pack_bf16x2(float a, float b) {
    unsigned ua = __float_as_uint(a);
    ua = (ua + 0x7FFF + ((ua >> 16) & 1)) >> 16;
    unsigned ub = __float_as_uint(b);
    ub = (ub + 0x7FFF + ((ub >> 16) & 1)) & 0xFFFF0000u;
    return ua | ub;
}

// Normalize d2 -> bf16 ws (row-major [NB*N2][128]).
__global__ void normalize_d2(const float* __restrict__ d2,
                             unsigned short* __restrict__ ws) {
    const int row = blockIdx.x * 8 + (threadIdx.x >> 5);
    const int l   = threadIdx.x & 31;
    const float4 v = *reinterpret_cast<const float4*>(d2 + (size_t)row * DD + l * 4);
    float ss = v.x * v.x + v.y * v.y + v.z * v.z + v.w * v.w;
    #pragma unroll
    for (int off = 16; off; off >>= 1) ss += __shfl_xor(ss, off);
    const float s = rsqrtf(ss);
    uint2 w;
    w.x = pack_bf16x2(v.x * s, v.y * s);
    w.y = pack_bf16x2(v.z * s, v.w * s);
    *reinterpret_cast<uint2*>(ws + (size_t)row * DD + l * 4) = w;
}

// GEMM with fused A-normalize. One block = 64(M) x 1024(N) output slab.
// R6 structure with two changes:
//  (1) LDS 48KB (B double-buffer 2x16KB + A 16KB) -> 3 blocks/CU (144KB/CU),
//      a third independent barrier domain to fill lockstep bubbles.
//      Depth-1 prefetch: stage(nj+1) issued mid-iter, waited via counted
//      vmcnt(16) (16 newest = this iter's output stores stay in flight).
//  (2) Non-temporal output stores: output is never re-read; NT keeps L2
//      from caching 134MB of dead lines (R10 counters proved traffic is
//      already minimal, so the only L2 lever left is retention policy).
__global__ __launch_bounds__(256, 3)
void gemm_kernel(const float* __restrict__ d3,
                 const unsigned short* __restrict__ d2n,
                 float* __restrict__ out) {
    __shared__ __align__(16) char smem[49152]; // B0:[0,16K) B1:[16K,32K) A:[32K,48K)

    // Bijective XCD swizzle: 512 = 8 XCDs x 64; each XCD owns 2 whole batches.
    const int hw  = blockIdx.x;
    const int blk = (hw & 7) * 64 + (hw >> 3);
    const int b   = blk >> 5;           // batch
    const int ti  = blk & 31;           // M tile (64 rows of N3=2048)
    const int t   = threadIdx.x;

    const float* gA = d3 + (size_t)(b * N3 + ti * 64) * DD;
    const char*  gB = (const char*)d2n + ((size_t)(b * N2) << 8);  // 256 B/row

    char* const aLds = smem + 32768;

    auto stage = [&](int c) {   // 16 KB: 4 x 256thr x 16B, pre-swizzled source
        const char* src = gB + (size_t)c * 16384;
        char* dst = smem + 16384 * (c & 1);
        #pragma unroll
        for (int it = 0; it < 4; ++it) {
            int o    = it * 4096 + t * 16;
            int row  = o >> 8;
            int scol = (o & 255) ^ ((row & 7) << 4);
            __builtin_amdgcn_global_load_lds(
                (const __attribute__((address_space(1))) void*)(src + row * 256 + scol),
                (__attribute__((address_space(3))) void*)(dst + o), 16, 0, 0);
        }
    };

    // ---- Prologue: A f32 loads + chunk-0 stage ----
    const int arow  = t >> 2;      // 0..63
    const int apart = t & 3;       // 32-f32 part of the 128-f32 row
    float4 av[8];
    #pragma unroll
    for (int i = 0; i < 8; ++i)
        av[i] = *reinterpret_cast<const float4*>(gA + (size_t)arow * DD + apart * 32 + i * 4);
    stage(0);

    // A: norm (4 lanes/row) -> bf16 -> swizzled LDS (st-16x32).
    {
        float ss = 0.f;
        #pragma unroll
        for (int i = 0; i < 8; ++i)
            ss += av[i].x * av[i].x + av[i].y * av[i].y + av[i].z * av[i].z + av[i].w * av[i].w;
        ss += __shfl_xor(ss, 1);
        ss += __shfl_xor(ss, 2);
        const float s = rsqrtf(ss);
        const int aswz = (arow & 7) << 4;
        #pragma unroll
        for (int j = 0; j < 4; ++j) {
            uint4 w;
            w.x = pack_bf16x2(av[2 * j].x * s,     av[2 * j].y * s);
            w.y = pack_bf16x2(av[2 * j].z * s,     av[2 * j].w * s);
            w.z = pack_bf16x2(av[2 * j + 1].x * s, av[2 * j + 1].y * s);
            w.w = pack_bf16x2(av[2 * j + 1].z * s, av[2 * j + 1].w * s);
            int colb = apart * 64 + j * 16;
            *reinterpret_cast<uint4*>(aLds + arow * 256 + (colb ^ aswz)) = w;
        }
    }
    asm volatile("s_waitcnt vmcnt(0) lgkmcnt(0)" ::: "memory");
    __builtin_amdgcn_s_barrier();
    __builtin_amdgcn_sched_barrier(0);

    // ---- Hoist this wave's A fragments (its own 16 rows). ----
    const int wid = t >> 6;             // 4 waves
    const int l   = t & 63;
    const int wm  = wid * 16;           // wave's 16-row band
    const int lr  = l & 15;
    const int kq  = l >> 4;
    const int sw  = (lr & 7) << 4;

    bf16x8 af[4];   // [ks]
    #pragma unroll
    for (int ks = 0; ks < 4; ++ks) {
        const int kb = ks * 64 + kq * 16;
        af[ks] = *reinterpret_cast<const bf16x8*>(aLds + (wm + lr) * 256 + (kb ^ sw));
    }

    float* obase = out + (size_t)b * OROWS * OCOLS + (size_t)(ti * 64) * OCOLS;

    // ---- Main loop: 16 chunks, double buffer, depth-1 prefetch ----
    for (int nj = 0; nj < 16; ++nj) {
        const char* bbuf = smem + 16384 * (nj & 1);

        f32x4 acc[4] = {};   // [ni] : cols ni*16+lr of the 64-col chunk
        #pragma unroll
        for (int ks = 0; ks < 4; ++ks) {
            const int kb = ks * 64 + kq * 16;
            #pragma unroll
            for (int ni = 0; ni < 4; ++ni) {
                bf16x8 bfr = *reinterpret_cast<const bf16x8*>(
                    bbuf + (ni * 16 + lr) * 256 + (kb ^ sw));
                acc[ni] = __builtin_amdgcn_mfma_f32_16x16x32_bf16(
                    af[ks], bfr, acc[ni], 0, 0, 0);
            }
        }

        // Prefetch next chunk into the other buffer (freed at the END of the
        // previous iteration's barrier -> safe to overwrite now).
        if (nj + 1 < 16) stage(nj + 1);

        // Stores (C/D: col=lane&15, row=(lane>>4)*4+reg), NON-TEMPORAL.
        #pragma unroll
        for (int i = 0; i < 4; ++i) {
            int r = wm + kq * 4 + i;
            #pragma unroll
            for (int ni = 0; ni < 4; ++ni) {
                int c = nj * 64 + ni * 16 + lr;
                __builtin_nontemporal_store(acc[ni][i],
                                            &obase[(size_t)r * OCOLS + c]);
            }
        }

        // FIFO wait: newest-16 = this iter's stores -> stage(nj+1)'s 4 loads
        // (older) retired; stores stay in flight across the barrier.
        if (nj + 1 < 16) {
            asm volatile("s_waitcnt vmcnt(16)" ::: "memory");
            __builtin_amdgcn_s_barrier();
            __builtin_amdgcn_sched_barrier(0);
        }
    }

    // Dustbin: col 1024 for this slab's 64 rows; row 2048 once per batch.
    if (t < 64)
        obase[(size_t)t * OCOLS + N2] = 0.0f;
    if (ti == 31) {
        float* last = out + (size_t)b * OROWS * OCOLS + (size_t)N3 * OCOLS;
        for (int c = t; c < OCOLS; c += 256) last[c] = 0.0f;
    }
}

extern "C" void kernel_launch(void* const* d_in, const int* in_sizes, int n_in,
                              void* d_out, int out_size, void* d_ws, size_t ws_size,
                              hipStream_t stream) {
    (void)in_sizes; (void)n_in; (void)out_size; (void)ws_size;
    const float* desc2d = (const float*)d_in[0];
    const float* desc3d = (const float*)d_in[2];

    unsigned short* d2n = (unsigned short*)d_ws;   // [NB*N2][128] bf16 = 4 MB
    float* out = (float*)d_out;

    normalize_d2<<<(NB * N2) / 8, 256, 0, stream>>>(desc2d, d2n);
    gemm_kernel<<<NB * (N3 / 64), 256, 0, stream>>>(desc3d, d2n, out);
}

// Round 12
// 39.328 us; speedup vs baseline: 2.4067x; 2.4067x over previous
//
#include <hip/hip_runtime.h>
#include <hip/hip_bf16.h>

// Problem constants (from reference): B=16, N2=1024, N3=2048, D=128
#define NB   16
#define N2   1024
#define N3   2048
#define DD   128
#define OROWS (N3 + 1)   // 2049
#define OCOLS (N2 + 1)   // 1025

typedef __attribute__((ext_vector_type(8))) __bf16 bf16x8;
typedef __attribute__((ext_vector_type(4))) float  f32x4;

// Pack two f32 into one u32 of 2x bf16 (RNE). a -> low half, b -> high half.
static __device__ __forceinline__ unsigned pack_bf16x2(float a, float b) {
    unsigned ua = __float_as_uint(a);
    ua = (ua + 0x7FFF + ((ua >> 16) & 1)) >> 16;
    unsigned ub = __float_as_uint(b);
    ub = (ub + 0x7FFF + ((ub >> 16) & 1)) & 0xFFFF0000u;
    return ua | ub;
}

// Normalize d2 -> bf16 ws (row-major [NB*N2][128]).
__global__ void normalize_d2(const float* __restrict__ d2,
                             unsigned short* __restrict__ ws) {
    const int row = blockIdx.x * 8 + (threadIdx.x >> 5);
    const int l   = threadIdx.x & 31;
    const float4 v = *reinterpret_cast<const float4*>(d2 + (size_t)row * DD + l * 4);
    float ss = v.x * v.x + v.y * v.y + v.z * v.z + v.w * v.w;
    #pragma unroll
    for (int off = 16; off; off >>= 1) ss += __shfl_xor(ss, off);
    const float s = rsqrtf(ss);
    uint2 w;
    w.x = pack_bf16x2(v.x * s, v.y * s);
    w.y = pack_bf16x2(v.z * s, v.w * s);
    *reinterpret_cast<uint2*>(ws + (size_t)row * DD + l * 4) = w;
}

// GEMM with fused A-normalize. One block = 64(M) x 1024(N) output slab.
// R6 structure, but B chunk = 32 cols (8KB): LDS = 3x8KB ring + 16KB A
// = 40KB -> 4 BLOCKS/CU (160KB exactly), 16 waves/CU in 4 independent
// barrier domains (R11 lesson: NT stores and depth-1 waits are poison;
// normal L2 write-back stores, depth-2 prefetch retained).
// Steady-state wait vmcnt(10) = {2 loads(nj+2), 8 stores(nj)}: the loads
// being waited on (nj+1's) were issued a FULL iteration earlier.
__global__ __launch_bounds__(256, 4)
void gemm_kernel(const float* __restrict__ d3,
                 const unsigned short* __restrict__ d2n,
                 float* __restrict__ out) {
    __shared__ __align__(16) char smem[40960]; // ring 3x8KB [0,24K), A [24K,40K)

    // Bijective XCD swizzle: 512 = 8 XCDs x 64; each XCD owns 2 whole batches.
    const int hw  = blockIdx.x;
    const int blk = (hw & 7) * 64 + (hw >> 3);
    const int b   = blk >> 5;           // batch
    const int ti  = blk & 31;           // M tile (64 rows of N3=2048)
    const int t   = threadIdx.x;

    const float* gA = d3 + (size_t)(b * N3 + ti * 64) * DD;
    const char*  gB = (const char*)d2n + ((size_t)(b * N2) << 8);  // 256 B/row

    char* const aLds = smem + 24576;

    auto stage = [&](int c) {   // 8 KB: 2 x 256thr x 16B, pre-swizzled source
        const char* src = gB + (size_t)c * 8192;
        char* dst = smem + 8192 * (c % 3);
        #pragma unroll
        for (int it = 0; it < 2; ++it) {
            int o    = it * 4096 + t * 16;
            int row  = o >> 8;          // 0..31
            int scol = (o & 255) ^ ((row & 7) << 4);
            __builtin_amdgcn_global_load_lds(
                (const __attribute__((address_space(1))) void*)(src + row * 256 + scol),
                (__attribute__((address_space(3))) void*)(dst + o), 16, 0, 0);
        }
    };

    // ---- Prologue: A f32 loads + chunk-0 stage ----
    const int arow  = t >> 2;      // 0..63
    const int apart = t & 3;       // 32-f32 part of the 128-f32 row
    float4 av[8];
    #pragma unroll
    for (int i = 0; i < 8; ++i)
        av[i] = *reinterpret_cast<const float4*>(gA + (size_t)arow * DD + apart * 32 + i * 4);
    stage(0);

    // A: norm (4 lanes/row) -> bf16 -> swizzled LDS (st-16x32).
    {
        float ss = 0.f;
        #pragma unroll
        for (int i = 0; i < 8; ++i)
            ss += av[i].x * av[i].x + av[i].y * av[i].y + av[i].z * av[i].z + av[i].w * av[i].w;
        ss += __shfl_xor(ss, 1);
        ss += __shfl_xor(ss, 2);
        const float s = rsqrtf(ss);
        const int aswz = (arow & 7) << 4;
        #pragma unroll
        for (int j = 0; j < 4; ++j) {
            uint4 w;
            w.x = pack_bf16x2(av[2 * j].x * s,     av[2 * j].y * s);
            w.y = pack_bf16x2(av[2 * j].z * s,     av[2 * j].w * s);
            w.z = pack_bf16x2(av[2 * j + 1].x * s, av[2 * j + 1].y * s);
            w.w = pack_bf16x2(av[2 * j + 1].z * s, av[2 * j + 1].w * s);
            int colb = apart * 64 + j * 16;
            *reinterpret_cast<uint4*>(aLds + arow * 256 + (colb ^ aswz)) = w;
        }
    }
    asm volatile("s_waitcnt vmcnt(0) lgkmcnt(0)" ::: "memory");
    __builtin_amdgcn_s_barrier();
    __builtin_amdgcn_sched_barrier(0);

    // ---- Hoist this wave's A fragments (its own 16 rows; region is
    //      never overwritten afterwards, so no extra barrier). ----
    const int wid = t >> 6;             // 4 waves
    const int l   = t & 63;
    const int wm  = wid * 16;           // wave's 16-row band
    const int lr  = l & 15;
    const int kq  = l >> 4;
    const int sw  = (lr & 7) << 4;

    bf16x8 af[4];   // [ks]
    #pragma unroll
    for (int ks = 0; ks < 4; ++ks) {
        const int kb = ks * 64 + kq * 16;
        af[ks] = *reinterpret_cast<const bf16x8*>(aLds + (wm + lr) * 256 + (kb ^ sw));
    }

    float* obase = out + (size_t)b * OROWS * OCOLS + (size_t)(ti * 64) * OCOLS;

    // ---- Main loop: 32 chunks of 32 cols, 3-buffer ring, depth-2 ----
    for (int nj = 0; nj < 32; ++nj) {
        const char* bbuf = smem + 8192 * (nj % 3);

        f32x4 acc[2] = {};   // [ni] : cols ni*16+lr of the 32-col chunk
        #pragma unroll
        for (int ks = 0; ks < 4; ++ks) {
            const int kb = ks * 64 + kq * 16;
            #pragma unroll
            for (int ni = 0; ni < 2; ++ni) {
                bf16x8 bfr = *reinterpret_cast<const bf16x8*>(
                    bbuf + (ni * 16 + lr) * 256 + (kb ^ sw));
                acc[ni] = __builtin_amdgcn_mfma_f32_16x16x32_bf16(
                    af[ks], bfr, acc[ni], 0, 0, 0);
            }
        }

        // Prefetch: iter 0 fills the depth-2 pipe; iters 1..29 issue nj+2.
        if (nj == 0) { stage(1); stage(2); }
        else if (nj + 2 < 32) stage(nj + 2);

        // Stores (C/D: col=lane&15, row=(lane>>4)*4+reg): per row, the
        // 2 ni-stores are consecutive 64B segments (128B run).
        #pragma unroll
        for (int i = 0; i < 4; ++i) {
            int r = wm + kq * 4 + i;
            #pragma unroll
            for (int ni = 0; ni < 2; ++ni) {
                int c = nj * 32 + ni * 16 + lr;
                obase[(size_t)r * OCOLS + c] = acc[ni][i];
            }
        }

        // FIFO wait: newest-10 = {2 loads(nj+2), 8 stores(nj)} -> loads(nj+1)
        // (issued a full iteration ago) retired; stores stay in flight.
        if (nj < 30) {
            asm volatile("s_waitcnt vmcnt(10)" ::: "memory");
            __builtin_amdgcn_s_barrier();
            __builtin_amdgcn_sched_barrier(0);
        } else if (nj == 30) {
            asm volatile("s_waitcnt vmcnt(8)" ::: "memory");
            __builtin_amdgcn_s_barrier();
            __builtin_amdgcn_sched_barrier(0);
        }
    }

    // Dustbin: col 1024 for this slab's 64 rows; row 2048 once per batch.
    if (t < 64)
        obase[(size_t)t * OCOLS + N2] = 0.0f;
    if (ti == 31) {
        float* last = out + (size_t)b * OROWS * OCOLS + (size_t)N3 * OCOLS;
        for (int c = t; c < OCOLS; c += 256) last[c] = 0.0f;
    }
}

extern "C" void kernel_launch(void* const* d_in, const int* in_sizes, int n_in,
                              void* d_out, int out_size, void* d_ws, size_t ws_size,
                              hipStream_t stream) {
    (void)in_sizes; (void)n_in; (void)out_size; (void)ws_size;
    const float* desc2d = (const float*)d_in[0];
    const float* desc3d = (const float*)d_in[2];

    unsigned short* d2n = (unsigned short*)d_ws;   // [NB*N2][128] bf16 = 4 MB
    float* out = (float*)d_out;

    normalize_d2<<<(NB * N2) / 8, 256, 0, stream>>>(desc2d, d2n);
    gemm_kernel<<<NB * (N3 / 64), 256, 0, stream>>>(desc3d, d2n, out);
}